// Round 1
// baseline (166.865 us; speedup 1.0000x reference)
//
#include <hip/hip_runtime.h>
#include <math.h>

// Problem constants (fixed by setup_inputs)
constexpr int N_ = 8, C_ = 256, F_ = 16, WH_ = 784;
constexpr int CH_STRIDE = F_ * WH_;        // 12544 floats between channels
constexpr int COUT_SZ = N_ * F_ * WH_;     // 100352 floats (c output)

__device__ inline float wave_reduce_sum(float v) {
#pragma unroll
  for (int o = 32; o > 0; o >>= 1) v += __shfl_down(v, o, 64);
  return v;
}
__device__ inline float wave_reduce_max(float v) {
#pragma unroll
  for (int o = 32; o > 0; o >>= 1) v = fmaxf(v, __shfl_down(v, o, 64));
  return v;
}

// One block per (n, f). 1024 threads = 16 waves.
__global__ __launch_bounds__(1024) void mfla_kernel(
    const float* __restrict__ l, const float* __restrict__ g,
    const float* __restrict__ w, float* __restrict__ out) {
  __shared__ float w_s[C_];
  __shared__ float e_s[WH_];   // unnormalized softmax numerators
  __shared__ float red_s[16];  // per-wave partials
  __shared__ float bc_s;       // broadcast slot

  const int b = blockIdx.x;    // b = n*16 + f
  const int n = b >> 4;
  const int f = b & 15;
  const int tid = threadIdx.x;
  const int lane = tid & 63;
  const int wv = tid >> 6;

  if (tid < C_) w_s[tid] = w[tid];

  // gb = sum_c g[n,c] * w[c]  (per-n scalar; softmax-invariant but part of c)
  float gv = (tid < C_) ? g[n * C_ + tid] * w[tid] : 0.f;
  gv = wave_reduce_sum(gv);
  if (lane == 0) red_s[wv] = gv;
  __syncthreads();  // also makes w_s visible
  if (tid == 0) {
    float s = 0.f;
#pragma unroll
    for (int i = 0; i < 16; ++i) s += red_s[i];
    bc_s = s;
  }
  __syncthreads();
  const float gb = bc_s;

  // ---- Pass A: c[p] = dot(l[n,:,f,p], w) + gb ----
  const size_t base_nf = (size_t)(n * C_ * F_ + f) * WH_;
  float cv = -3.4e38f;
  if (tid < WH_) {
    const float* lp = l + base_nf + tid;
    float acc = 0.f;
#pragma unroll 8
    for (int c = 0; c < C_; ++c) acc = fmaf(lp[(size_t)c * CH_STRIDE], w_s[c], acc);
    cv = acc + gb;
    out[b * WH_ + tid] = cv;  // raw compatibility map output
  }

  // ---- softmax over the 784 spatial positions ----
  float m = wave_reduce_max(cv);
  __syncthreads();  // red_s/bc_s reuse safety
  if (lane == 0) red_s[wv] = m;
  __syncthreads();
  if (tid == 0) {
    float mm = red_s[0];
#pragma unroll
    for (int i = 1; i < 16; ++i) mm = fmaxf(mm, red_s[i]);
    bc_s = mm;
  }
  __syncthreads();
  const float cmax = bc_s;

  float e = 0.f;
  if (tid < WH_) {
    e = expf(cv - cmax);
    e_s[tid] = e;
  }
  float s = wave_reduce_sum(e);
  __syncthreads();
  if (lane == 0) red_s[wv] = s;
  __syncthreads();
  if (tid == 0) {
    float ss = 0.f;
#pragma unroll
    for (int i = 0; i < 16; ++i) ss += red_s[i];
    bc_s = 1.f / ss;
  }
  __syncthreads();
  const float inv_sum = bc_s;  // fold normalization into final store

  // ---- Pass B: g_out[n,c,f] = sum_p a[p] * l[n,c,f,p] ----
  // Preload this wave's slice of e_s into registers (same for all channels).
  const int p0 = lane << 2;
  const float4 ew0 = *reinterpret_cast<const float4*>(&e_s[p0]);
  const float4 ew1 = *reinterpret_cast<const float4*>(&e_s[p0 + 256]);
  const float4 ew2 = *reinterpret_cast<const float4*>(&e_s[p0 + 512]);
  float4 ew3 = make_float4(0.f, 0.f, 0.f, 0.f);
  if (lane < 4) ew3 = *reinterpret_cast<const float4*>(&e_s[768 + p0]);

#pragma unroll 1
  for (int i = 0; i < 16; ++i) {
    const int c = wv + (i << 4);  // wave wv handles channels wv, wv+16, ...
    const float* bp = l + ((size_t)(n * C_ + c) * F_ + f) * WH_;
    float4 lv0 = *reinterpret_cast<const float4*>(bp + p0);
    float4 lv1 = *reinterpret_cast<const float4*>(bp + p0 + 256);
    float4 lv2 = *reinterpret_cast<const float4*>(bp + p0 + 512);
    float4 lv3 = make_float4(0.f, 0.f, 0.f, 0.f);
    if (lane < 4) lv3 = *reinterpret_cast<const float4*>(bp + 768 + p0);

    float acc = 0.f;
    acc = fmaf(lv0.x, ew0.x, acc); acc = fmaf(lv0.y, ew0.y, acc);
    acc = fmaf(lv0.z, ew0.z, acc); acc = fmaf(lv0.w, ew0.w, acc);
    acc = fmaf(lv1.x, ew1.x, acc); acc = fmaf(lv1.y, ew1.y, acc);
    acc = fmaf(lv1.z, ew1.z, acc); acc = fmaf(lv1.w, ew1.w, acc);
    acc = fmaf(lv2.x, ew2.x, acc); acc = fmaf(lv2.y, ew2.y, acc);
    acc = fmaf(lv2.z, ew2.z, acc); acc = fmaf(lv2.w, ew2.w, acc);
    acc = fmaf(lv3.x, ew3.x, acc); acc = fmaf(lv3.y, ew3.y, acc);
    acc = fmaf(lv3.z, ew3.z, acc); acc = fmaf(lv3.w, ew3.w, acc);

    acc = wave_reduce_sum(acc);
    if (lane == 0)
      out[COUT_SZ + (size_t)(n * C_ + c) * F_ + f] = acc * inv_sum;
  }
}

extern "C" void kernel_launch(void* const* d_in, const int* in_sizes, int n_in,
                              void* d_out, int out_size, void* d_ws, size_t ws_size,
                              hipStream_t stream) {
  const float* l = (const float*)d_in[0];
  const float* g = (const float*)d_in[1];
  const float* w = (const float*)d_in[2];
  float* out = (float*)d_out;
  mfla_kernel<<<dim3(N_ * F_), dim3(1024), 0, stream>>>(l, g, w, out);
}